// Round 1
// baseline (15519.849 us; speedup 1.0000x reference)
//
#include <hip/hip_runtime.h>

#define B_ 64
#define T_ 512
#define D_ 512
#define H_ 512
#define NG 2048  // 4H

typedef __attribute__((ext_vector_type(8))) short short8;
typedef __attribute__((ext_vector_type(4))) float floatx4;

static __device__ __forceinline__ unsigned short f2bf(float f) {
    unsigned int u = __float_as_uint(f);
    return (unsigned short)((u + 0x7FFFu + ((u >> 16) & 1u)) >> 16);  // RNE
}

static __device__ __forceinline__ short8 pack8(float4 a, float4 b) {
    short8 r;
    r[0] = (short)f2bf(a.x); r[1] = (short)f2bf(a.y);
    r[2] = (short)f2bf(a.z); r[3] = (short)f2bf(a.w);
    r[4] = (short)f2bf(b.x); r[5] = (short)f2bf(b.y);
    r[6] = (short)f2bf(b.z); r[7] = (short)f2bf(b.w);
    return r;
}

static __device__ __forceinline__ float sigm(float x) { return 1.0f / (1.0f + __expf(-x)); }
static __device__ __forceinline__ float tanh_(float x) {
    float e = __expf(2.0f * x);
    return 1.0f - 2.0f / (e + 1.0f);
}

// ---- transpose Wi/Wh ([512][2048] f32) -> bf16 [2048][512] (k-contig for MFMA B frags) ----
__global__ __launch_bounds__(256) void transpose_w(
    const float* __restrict__ Wi, const float* __restrict__ Wh,
    unsigned short* __restrict__ WiT, unsigned short* __restrict__ WhT)
{
    int tid = blockIdx.x * 256 + threadIdx.x;   // 2048*512 threads
    int n = tid >> 9;
    int k = tid & 511;
    WiT[tid] = f2bf(Wi[(size_t)k * NG + n]);
    WhT[tid] = f2bf(Wh[(size_t)k * NG + n]);
}

// ---- zx[b][t][4H] (fp16) = flip(x) @ Wi + b ; 128x128 tile, 4 waves, 16x16x32 bf16 MFMA ----
__global__ __launch_bounds__(256) void zx_gemm(
    const float* __restrict__ x, const int* __restrict__ lengths,
    const unsigned short* __restrict__ WiT, const float* __restrict__ bias,
    const int* __restrict__ revp, _Float16* __restrict__ zx)
{
    __shared__ unsigned short a_lds[128][40];  // +8 pad: 80B row stride -> 2-way max
    __shared__ unsigned short b_lds[128][40];

    const int mt = blockIdx.x, nt = blockIdx.y;
    const int tid = threadIdx.x;
    const int lane = tid & 63, w = tid >> 6;
    const int wm = w & 1, wn = w >> 1;

    const int b = mt >> 2;                 // 4 m-tiles per batch (512 rows/batch)
    const int len = lengths[b];
    const int rev = revp[0];

    const int r = tid >> 1;                // 0..127 (A row / B col)
    const int kh = (tid & 1) << 4;         // 0 or 16
    const int t = ((mt & 3) << 7) + r;
    const int src_t = rev ? ((T_ - 1 - t + len) & (T_ - 1)) : t;
    const float* arow = x + ((size_t)b * T_ + src_t) * D_;
    const unsigned short* brow = WiT + (size_t)(nt * 128 + r) * D_;

    floatx4 acc[4][4];
#pragma unroll
    for (int i = 0; i < 4; ++i)
#pragma unroll
        for (int j = 0; j < 4; ++j) acc[i][j] = (floatx4){0.f, 0.f, 0.f, 0.f};

    for (int kt = 0; kt < D_ / 32; ++kt) {
        const float4* ap = (const float4*)(arow + kt * 32 + kh);
        float4 a0 = ap[0], a1 = ap[1], a2 = ap[2], a3 = ap[3];
        const uint4* bp = (const uint4*)(brow + kt * 32 + kh);
        uint4 bq0 = bp[0], bq1 = bp[1];
        *(short8*)&a_lds[r][kh]     = pack8(a0, a1);
        *(short8*)&a_lds[r][kh + 8] = pack8(a2, a3);
        *(uint4*)&b_lds[r][kh]     = bq0;
        *(uint4*)&b_lds[r][kh + 8] = bq1;
        __syncthreads();

        short8 af[4], bfr[4];
#pragma unroll
        for (int mi = 0; mi < 4; ++mi)
            af[mi] = *(const short8*)&a_lds[wm * 64 + mi * 16 + (lane & 15)][(lane >> 4) << 3];
#pragma unroll
        for (int ni = 0; ni < 4; ++ni)
            bfr[ni] = *(const short8*)&b_lds[wn * 64 + ni * 16 + (lane & 15)][(lane >> 4) << 3];
#pragma unroll
        for (int mi = 0; mi < 4; ++mi)
#pragma unroll
            for (int ni = 0; ni < 4; ++ni)
                acc[mi][ni] = __builtin_amdgcn_mfma_f32_16x16x32_bf16(af[mi], bfr[ni], acc[mi][ni], 0, 0, 0);
        __syncthreads();
    }

    // epilogue: D row = 4*(lane>>4)+v, col = lane&15 (measured m89 layout); add bias, store fp16
#pragma unroll
    for (int mi = 0; mi < 4; ++mi) {
#pragma unroll
        for (int ni = 0; ni < 4; ++ni) {
            int row = wm * 64 + mi * 16 + ((lane >> 4) << 2);
            int col = nt * 128 + wn * 64 + ni * 16 + (lane & 15);
            float bv = bias[col];
            size_t base = (size_t)(mt * 128 + row) * NG + col;
#pragma unroll
            for (int v = 0; v < 4; ++v)
                zx[base + (size_t)v * NG] = (_Float16)(acc[mi][ni][v] + bv);
        }
    }
}

// ---- persistent LSTM recurrence: 256 blocks = 8 batch-groups x 32 hidden-groups ----
__global__ __launch_bounds__(256, 1) void lstm_rec(
    const _Float16* __restrict__ zx, const unsigned short* __restrict__ WhT,
    const float* __restrict__ c0, const float* __restrict__ h0,
    const int* __restrict__ lengths, const int* __restrict__ revp,
    float* __restrict__ out, unsigned short* __restrict__ h_state,
    unsigned int* __restrict__ flags)
{
    __shared__ unsigned short h_lds[16][520];  // rows 8..15 zero (MFMA M=16, 8 real batches)
    __shared__ float zred[4][8][64];
    __shared__ float c_st[8][16];

    const int bid = blockIdx.x;
    const int gb = bid & 7, gh = bid >> 3;     // same gb -> same XCD under round-robin dispatch
    const int tid = threadIdx.x;
    const int lane = tid & 63, w = tid >> 6;
    const int b0 = gb * 8, u0 = gh * 16;
    const int rev = revp[0];

    for (int i = tid; i < 8 * 520; i += 256)
        h_lds[8 + i / 520][i % 520] = 0;

    const int bi = (tid < 128) ? (tid >> 4) : 0;
    const int jj = tid & 15;
    int len_b = 0;
    if (tid < 128) {
        c_st[bi][jj] = c0[(size_t)(b0 + bi) * H_ + u0 + jj];
        len_b = lengths[b0 + bi];
    }

    // Wh fragments resident in registers: wave w owns k in [w*128, (w+1)*128)
    // col-local = ni*16 + (lane&15): ni == gate index, (lane&15) == unit within group
    short8 bw[4][4];
    {
        const int colh = lane & 15;
        const int khw = (lane >> 4) << 3;
#pragma unroll
        for (int ni = 0; ni < 4; ++ni) {
            const unsigned short* src = WhT + (size_t)(ni * H_ + u0 + colh) * D_ + w * 128 + khw;
#pragma unroll
            for (int kk = 0; kk < 4; ++kk)
                bw[ni][kk] = *(const short8*)(src + kk * 32);
        }
    }

    const int sr = tid >> 5;            // staging: 32 threads/row, 16 bf16 each
    const int soff = (tid & 31) << 4;

    float zxv[4];
    if (tid < 128) {
        const _Float16* zp = zx + ((size_t)(b0 + bi) * T_) * NG + u0 + jj;
#pragma unroll
        for (int g = 0; g < 4; ++g) zxv[g] = (float)zp[g * H_];
    }

    for (int s = 0; s < T_; ++s) {
        // ---- stage h[8][512] -> LDS ----
        if (s == 0) {
            const float4* hp = (const float4*)(h0 + (size_t)(b0 + sr) * H_ + soff);
            float4 v0 = hp[0], v1 = hp[1], v2 = hp[2], v3 = hp[3];
            *(short8*)&h_lds[sr][soff]     = pack8(v0, v1);
            *(short8*)&h_lds[sr][soff + 8] = pack8(v2, v3);
        } else {
            const uint4* hp = (const uint4*)(h_state + ((size_t)(s & 1) * B_ + b0 + sr) * H_ + soff);
            uint4 v0 = hp[0], v1 = hp[1];
            *(uint4*)&h_lds[sr][soff]     = v0;
            *(uint4*)&h_lds[sr][soff + 8] = v1;
        }
        __syncthreads();

        // ---- z_partial = h @ Wh-slice (per-wave K-quarter) ----
        floatx4 acc[4];
#pragma unroll
        for (int ni = 0; ni < 4; ++ni) acc[ni] = (floatx4){0.f, 0.f, 0.f, 0.f};
        {
            const int row = lane & 15;
            const int khw = (lane >> 4) << 3;
#pragma unroll
            for (int kk = 0; kk < 4; ++kk) {
                short8 af = *(const short8*)&h_lds[row][w * 128 + kk * 32 + khw];
#pragma unroll
                for (int ni = 0; ni < 4; ++ni)
                    acc[ni] = __builtin_amdgcn_mfma_f32_16x16x32_bf16(af, bw[ni][kk], acc[ni], 0, 0, 0);
            }
        }
        {
            const int rr = (lane >> 4) << 2;
            if (rr < 8) {
#pragma unroll
                for (int ni = 0; ni < 4; ++ni)
#pragma unroll
                    for (int v = 0; v < 4; ++v)
                        zred[w][rr + v][ni * 16 + (lane & 15)] = acc[ni][v];
            }
        }
        __syncthreads();

        // ---- gates + state update (fp32) ----
        if (tid < 128) {
            float z[4];
#pragma unroll
            for (int g = 0; g < 4; ++g) {
                int c = g * 16 + jj;
                z[g] = zxv[g] + zred[0][bi][c] + zred[1][bi][c] + zred[2][bi][c] + zred[3][bi][c];
            }
            float ig = sigm(z[0]), fg = sigm(z[1]);
            float gg = tanh_(z[2]), og = sigm(z[3]);
            float cn = fg * c_st[bi][jj] + ig * gg;
            float hn = og * tanh_(cn);
            c_st[bi][jj] = cn;
            int orig_t = rev ? ((T_ - 1 - s + len_b) & (T_ - 1)) : s;   // flip is an involution
            out[((size_t)(b0 + bi) * T_ + orig_t) * H_ + u0 + jj] = hn;
            h_state[((size_t)((s + 1) & 1) * B_ + b0 + bi) * H_ + u0 + jj] = f2bf(hn);
            if (s == len_b - 1) {
                size_t fin = (size_t)B_ * T_ * H_;
                out[fin + (size_t)(b0 + bi) * H_ + u0 + jj] = cn;
                out[fin + (size_t)B_ * H_ + (size_t)(b0 + bi) * H_ + u0 + jj] = hn;
            }
        }

        // ---- batch-group barrier (32 blocks) + zx prefetch under the spin ----
        if (s + 1 < T_) {
            __syncthreads();   // drains vmcnt -> h_state/out stores complete
            if (tid < 128) {
                const _Float16* zp = zx + ((size_t)(b0 + bi) * T_ + (s + 1)) * NG + u0 + jj;
#pragma unroll
                for (int g = 0; g < 4; ++g) zxv[g] = (float)zp[g * H_];
            }
            if (tid == 0)
                __hip_atomic_fetch_add(&flags[s * 8 + gb], 1u, __ATOMIC_RELEASE, __HIP_MEMORY_SCOPE_AGENT);
            while (__hip_atomic_load(&flags[s * 8 + gb], __ATOMIC_ACQUIRE, __HIP_MEMORY_SCOPE_AGENT) < 32u)
                __builtin_amdgcn_s_sleep(1);
        }
    }
}

extern "C" void kernel_launch(void* const* d_in, const int* in_sizes, int n_in,
                              void* d_out, int out_size, void* d_ws, size_t ws_size,
                              hipStream_t stream)
{
    const float* x       = (const float*)d_in[0];
    const int*   lengths = (const int*)d_in[1];
    const float* c0      = (const float*)d_in[2];
    const float* h0      = (const float*)d_in[3];
    const float* Wi      = (const float*)d_in[4];
    const float* Wh      = (const float*)d_in[5];
    const float* bias    = (const float*)d_in[6];
    const int*   revp    = (const int*)d_in[7];
    float* out = (float*)d_out;

    char* ws = (char*)d_ws;
    const size_t OFF_WIT = 0;
    const size_t OFF_WHT = 2ull << 20;
    const size_t OFF_ZX  = 4ull << 20;
    const size_t OFF_H   = OFF_ZX + (size_t)B_ * T_ * NG * 2;   // 134,217,728 B of fp16 zx
    const size_t OFF_FLG = OFF_H + 2ull * B_ * H_ * 2;          // double-buffered bf16 h
    const size_t NEED    = OFF_FLG + (size_t)T_ * 8 * 4;
    if (ws_size < NEED) return;  // ws too small -> leaves poison (diagnosable)

    unsigned short* WiT = (unsigned short*)(ws + OFF_WIT);
    unsigned short* WhT = (unsigned short*)(ws + OFF_WHT);
    _Float16* zx        = (_Float16*)(ws + OFF_ZX);
    unsigned short* h_state = (unsigned short*)(ws + OFF_H);
    unsigned int* flags = (unsigned int*)(ws + OFF_FLG);

    hipMemsetAsync(flags, 0, (size_t)T_ * 8 * 4, stream);  // deterministic per replay
    transpose_w<<<4096, 256, 0, stream>>>(Wi, Wh, WiT, WhT);
    dim3 g1(256, 16);
    zx_gemm<<<g1, 256, 0, stream>>>(x, lengths, WiT, bias, revp, zx);
    lstm_rec<<<256, 256, 0, stream>>>(zx, WhT, c0, h0, lengths, revp, out, h_state, flags);
}

// Round 2
// 1712.092 us; speedup vs baseline: 9.0648x; 9.0648x over previous
//
#include <hip/hip_runtime.h>

#define B_ 64
#define T_ 512
#define D_ 512
#define H_ 512
#define NG 2048  // 4H

typedef __attribute__((ext_vector_type(8))) short short8;
typedef __attribute__((ext_vector_type(4))) float floatx4;

static __device__ __forceinline__ unsigned short f2bf(float f) {
    unsigned int u = __float_as_uint(f);
    return (unsigned short)((u + 0x7FFFu + ((u >> 16) & 1u)) >> 16);  // RNE
}

static __device__ __forceinline__ short8 pack8(float4 a, float4 b) {
    short8 r;
    r[0] = (short)f2bf(a.x); r[1] = (short)f2bf(a.y);
    r[2] = (short)f2bf(a.z); r[3] = (short)f2bf(a.w);
    r[4] = (short)f2bf(b.x); r[5] = (short)f2bf(b.y);
    r[6] = (short)f2bf(b.z); r[7] = (short)f2bf(b.w);
    return r;
}

static __device__ __forceinline__ float sigm(float x) { return 1.0f / (1.0f + __expf(-x)); }
static __device__ __forceinline__ float tanh_(float x) {
    float e = __expf(2.0f * x);
    return 1.0f - 2.0f / (e + 1.0f);
}

// ---- transpose Wi/Wh ([512][2048] f32) -> bf16 [2048][512], LDS-tiled (both sides coalesced) ----
__global__ __launch_bounds__(256) void transpose_w(
    const float* __restrict__ Wi, const float* __restrict__ Wh,
    unsigned short* __restrict__ WiT, unsigned short* __restrict__ WhT)
{
    __shared__ float tile[64][65];
    const float* src = blockIdx.z ? Wh : Wi;
    unsigned short* dst = blockIdx.z ? WhT : WiT;
    const int n0 = blockIdx.x * 64, k0 = blockIdx.y * 64;
    const int cx = threadIdx.x & 63, ry = threadIdx.x >> 6;
#pragma unroll
    for (int i = 0; i < 16; ++i) {
        int k = ry * 16 + i;
        tile[k][cx] = src[(size_t)(k0 + k) * NG + n0 + cx];
    }
    __syncthreads();
#pragma unroll
    for (int i = 0; i < 16; ++i) {
        int n = ry * 16 + i;
        dst[(size_t)(n0 + n) * D_ + k0 + cx] = f2bf(tile[cx][n]);
    }
}

// ---- zx[b][t][4H] (fp16) = flip(x) @ Wi + b ; 128x128 tile, 4 waves, 16x16x32 bf16 MFMA ----
__global__ __launch_bounds__(256) void zx_gemm(
    const float* __restrict__ x, const int* __restrict__ lengths,
    const unsigned short* __restrict__ WiT, const float* __restrict__ bias,
    const int* __restrict__ revp, _Float16* __restrict__ zx)
{
    __shared__ unsigned short a_lds[128][40];
    __shared__ unsigned short b_lds[128][40];

    const int mt = blockIdx.x, nt = blockIdx.y;
    const int tid = threadIdx.x;
    const int lane = tid & 63, w = tid >> 6;
    const int wm = w & 1, wn = w >> 1;

    const int b = mt >> 2;
    const int len = lengths[b];
    const int rev = revp[0];

    const int r = tid >> 1;
    const int kh = (tid & 1) << 4;
    const int t = ((mt & 3) << 7) + r;
    const int src_t = rev ? ((T_ - 1 - t + len) & (T_ - 1)) : t;
    const float* arow = x + ((size_t)b * T_ + src_t) * D_;
    const unsigned short* brow = WiT + (size_t)(nt * 128 + r) * D_;

    floatx4 acc[4][4];
#pragma unroll
    for (int i = 0; i < 4; ++i)
#pragma unroll
        for (int j = 0; j < 4; ++j) acc[i][j] = (floatx4){0.f, 0.f, 0.f, 0.f};

    for (int kt = 0; kt < D_ / 32; ++kt) {
        const float4* ap = (const float4*)(arow + kt * 32 + kh);
        float4 a0 = ap[0], a1 = ap[1], a2 = ap[2], a3 = ap[3];
        const uint4* bp = (const uint4*)(brow + kt * 32 + kh);
        uint4 bq0 = bp[0], bq1 = bp[1];
        *(short8*)&a_lds[r][kh]     = pack8(a0, a1);
        *(short8*)&a_lds[r][kh + 8] = pack8(a2, a3);
        *(uint4*)&b_lds[r][kh]     = bq0;
        *(uint4*)&b_lds[r][kh + 8] = bq1;
        __syncthreads();

        short8 af[4], bfr[4];
#pragma unroll
        for (int mi = 0; mi < 4; ++mi)
            af[mi] = *(const short8*)&a_lds[wm * 64 + mi * 16 + (lane & 15)][(lane >> 4) << 3];
#pragma unroll
        for (int ni = 0; ni < 4; ++ni)
            bfr[ni] = *(const short8*)&b_lds[wn * 64 + ni * 16 + (lane & 15)][(lane >> 4) << 3];
#pragma unroll
        for (int mi = 0; mi < 4; ++mi)
#pragma unroll
            for (int ni = 0; ni < 4; ++ni)
                acc[mi][ni] = __builtin_amdgcn_mfma_f32_16x16x32_bf16(af[mi], bfr[ni], acc[mi][ni], 0, 0, 0);
        __syncthreads();
    }

#pragma unroll
    for (int mi = 0; mi < 4; ++mi) {
#pragma unroll
        for (int ni = 0; ni < 4; ++ni) {
            int row = wm * 64 + mi * 16 + ((lane >> 4) << 2);
            int col = nt * 128 + wn * 64 + ni * 16 + (lane & 15);
            float bv = bias[col];
            size_t base = (size_t)(mt * 128 + row) * NG + col;
#pragma unroll
            for (int v = 0; v < 4; ++v)
                zx[base + (size_t)v * NG] = (_Float16)(acc[mi][ni][v] + bv);
        }
    }
}

// ---- persistent LSTM recurrence: 64 blocks = 8 batch-groups x 8 hidden-groups, 512 thr ----
// Block owns 8 batches x 64 h-units (256 gate cols). Wh slice register-resident.
// Cross-block exchange: relaxed agent atomics (coherence point), ordering via barrier vmcnt drains.
__global__ __launch_bounds__(512, 2) void lstm_rec(
    const _Float16* __restrict__ zx, const unsigned short* __restrict__ WhT,
    const float* __restrict__ c0, const float* __restrict__ h0,
    const int* __restrict__ lengths, const int* __restrict__ revp,
    float* __restrict__ out, unsigned short* __restrict__ h_state,
    unsigned int* __restrict__ flags)
{
    __shared__ unsigned short h_lds[16][520];   // rows 8..15 zero (MFMA M=16, 8 real batches)
    __shared__ float zred[8][8][256];           // [wave(K-slice)][batch][local gate col]
    __shared__ unsigned short h_next[8][64];

    const int bid = blockIdx.x;
    const int gb = bid & 7, gh = bid >> 3;
    const int tid = threadIdx.x;
    const int lane = tid & 63, w = tid >> 6;    // 8 waves; wave w owns K in [w*64, w*64+64)
    const int b0 = gb * 8, u0 = gh * 64;
    const int rev = revp[0];

    for (int i = tid; i < 8 * 520; i += 512)
        h_lds[8 + i / 520][i % 520] = 0;

    const int bi = tid >> 6;                    // gates-phase batch (== w)
    const int jj = tid & 63;                    // gates-phase unit
    const int len_b = lengths[b0 + bi];
    float c = c0[(size_t)(b0 + bi) * H_ + u0 + jj];

    // Wh fragments in registers: local col l = ni*16 + (lane&15); gate g=l>>6, unit l&63
    short8 bw[16][2];
    const int colh = lane & 15;
    const int khw = (lane >> 4) << 3;
#pragma unroll
    for (int ni = 0; ni < 16; ++ni) {
        const int l = ni * 16 + colh;
        const unsigned short* src =
            WhT + (size_t)((l >> 6) * H_ + u0 + (l & 63)) * D_ + w * 64 + khw;
        bw[ni][0] = *(const short8*)(src);
        bw[ni][1] = *(const short8*)(src + 32);
    }

    float zxv[4];
    {
        const _Float16* zp = zx + ((size_t)(b0 + bi) * T_) * NG + u0 + jj;
#pragma unroll
        for (int g = 0; g < 4; ++g) zxv[g] = (float)zp[g * H_];
    }

    const int sr = tid >> 6;            // staging: 64 threads/row, 8 bf16 (16B) each
    const int sc = (tid & 63) << 3;

    for (int s = 0; s < T_; ++s) {
        // ---- stage h[8][512] -> LDS (coherence-point loads) ----
        if (s == 0) {
            const float4* hp = (const float4*)(h0 + (size_t)(b0 + sr) * H_ + sc);
            float4 v0 = hp[0], v1 = hp[1];
            *(short8*)&h_lds[sr][sc] = pack8(v0, v1);
        } else {
            const unsigned long long* hp =
                (const unsigned long long*)(h_state + ((size_t)(s & 1) * B_ + b0 + sr) * H_ + sc);
            unsigned long long v0 = __hip_atomic_load(hp,     __ATOMIC_RELAXED, __HIP_MEMORY_SCOPE_AGENT);
            unsigned long long v1 = __hip_atomic_load(hp + 1, __ATOMIC_RELAXED, __HIP_MEMORY_SCOPE_AGENT);
            *(unsigned long long*)&h_lds[sr][sc]     = v0;
            *(unsigned long long*)&h_lds[sr][sc + 4] = v1;
        }
        __syncthreads();

        // ---- z_partial = h @ Wh-slice (wave w: K in [w*64, w*64+64)) ----
        floatx4 acc[16];
#pragma unroll
        for (int ni = 0; ni < 16; ++ni) acc[ni] = (floatx4){0.f, 0.f, 0.f, 0.f};
        {
            const int arow = lane & 15;
#pragma unroll
            for (int kk = 0; kk < 2; ++kk) {
                short8 af = *(const short8*)&h_lds[arow][w * 64 + kk * 32 + khw];
#pragma unroll
                for (int ni = 0; ni < 16; ++ni)
                    acc[ni] = __builtin_amdgcn_mfma_f32_16x16x32_bf16(af, bw[ni][kk], acc[ni], 0, 0, 0);
            }
        }
        {
            const int rr = (lane >> 4) << 2;    // D row = rr+v, col = ni*16+colh
            if (rr < 8) {
#pragma unroll
                for (int ni = 0; ni < 16; ++ni)
#pragma unroll
                    for (int v = 0; v < 4; ++v)
                        zred[w][rr + v][ni * 16 + colh] = acc[ni][v];
            }
        }
        __syncthreads();

        // ---- gates + state update: thread (bi,jj), c in register ----
        {
            float z[4];
#pragma unroll
            for (int g = 0; g < 4; ++g) {
                float a = zxv[g];
#pragma unroll
                for (int w2 = 0; w2 < 8; ++w2) a += zred[w2][bi][g * 64 + jj];
                z[g] = a;
            }
            float ig = sigm(z[0]), fg = sigm(z[1]);
            float gg = tanh_(z[2]), og = sigm(z[3]);
            float cn = fg * c + ig * gg;
            float hn = og * tanh_(cn);
            c = cn;
            int orig_t = rev ? ((T_ - 1 - s + len_b) & (T_ - 1)) : s;
            out[((size_t)(b0 + bi) * T_ + orig_t) * H_ + u0 + jj] = hn;
            h_next[bi][jj] = f2bf(hn);
            if (s == len_b - 1) {
                size_t fin = (size_t)B_ * T_ * H_;
                out[fin + (size_t)(b0 + bi) * H_ + u0 + jj] = cn;
                out[fin + (size_t)B_ * H_ + (size_t)(b0 + bi) * H_ + u0 + jj] = hn;
            }
        }
        __syncthreads();   // h_next visible

        if (s + 1 < T_) {
            // publish h (coherence-point stores) + prefetch zx for s+1
            if (tid < 256) {
                const int bi2 = tid >> 5, j2 = (tid & 31) << 1;
                unsigned int val = (unsigned int)h_next[bi2][j2] |
                                   ((unsigned int)h_next[bi2][j2 + 1] << 16);
                unsigned short* dst =
                    h_state + ((size_t)((s + 1) & 1) * B_ + b0 + bi2) * H_ + u0 + j2;
                __hip_atomic_store((unsigned int*)dst, val, __ATOMIC_RELAXED, __HIP_MEMORY_SCOPE_AGENT);
            }
            {
                const _Float16* zp = zx + ((size_t)(b0 + bi) * T_ + (s + 1)) * NG + u0 + jj;
#pragma unroll
                for (int g = 0; g < 4; ++g) zxv[g] = (float)zp[g * H_];
            }
            __syncthreads();   // per-wave vmcnt(0) drain: h stores globally visible
            if (tid == 0) {
                __hip_atomic_fetch_add(&flags[s * 8 + gb], 1u, __ATOMIC_RELAXED, __HIP_MEMORY_SCOPE_AGENT);
                while (__hip_atomic_load(&flags[s * 8 + gb], __ATOMIC_RELAXED, __HIP_MEMORY_SCOPE_AGENT) < 8u)
                    __builtin_amdgcn_s_sleep(1);
            }
            __syncthreads();
        }
    }
}

extern "C" void kernel_launch(void* const* d_in, const int* in_sizes, int n_in,
                              void* d_out, int out_size, void* d_ws, size_t ws_size,
                              hipStream_t stream)
{
    const float* x       = (const float*)d_in[0];
    const int*   lengths = (const int*)d_in[1];
    const float* c0      = (const float*)d_in[2];
    const float* h0      = (const float*)d_in[3];
    const float* Wi      = (const float*)d_in[4];
    const float* Wh      = (const float*)d_in[5];
    const float* bias    = (const float*)d_in[6];
    const int*   revp    = (const int*)d_in[7];
    float* out = (float*)d_out;

    char* ws = (char*)d_ws;
    const size_t OFF_WIT = 0;
    const size_t OFF_WHT = 2ull << 20;
    const size_t OFF_ZX  = 4ull << 20;
    const size_t OFF_H   = OFF_ZX + (size_t)B_ * T_ * NG * 2;
    const size_t OFF_FLG = OFF_H + 2ull * B_ * H_ * 2;
    const size_t NEED    = OFF_FLG + (size_t)T_ * 8 * 4;
    if (ws_size < NEED) return;

    unsigned short* WiT = (unsigned short*)(ws + OFF_WIT);
    unsigned short* WhT = (unsigned short*)(ws + OFF_WHT);
    _Float16* zx        = (_Float16*)(ws + OFF_ZX);
    unsigned short* h_state = (unsigned short*)(ws + OFF_H);
    unsigned int* flags = (unsigned int*)(ws + OFF_FLG);

    hipMemsetAsync(flags, 0, (size_t)T_ * 8 * 4, stream);
    dim3 gt(32, 8, 2);
    transpose_w<<<gt, 256, 0, stream>>>(Wi, Wh, WiT, WhT);
    dim3 g1(256, 16);
    zx_gemm<<<g1, 256, 0, stream>>>(x, lengths, WiT, bias, revp, zx);
    lstm_rec<<<64, 512, 0, stream>>>(zx, WhT, c0, h0, lengths, revp, out, h_state, flags);
}